// Round 1
// baseline (2910.541 us; speedup 1.0000x reference)
//
#include <hip/hip_runtime.h>

// ConvTranspose4d: x[4,64,12,12,12,12] (*) w[64,64,3,3,3,3], stride 2 -> out[4,64,25,25,25,25]
// Gather form: out[b,co,p1..p4] = bias[co] + sum_{ci, k1..k4 : p_d==2*i_d+k_d} x[b,ci,i1..i4]*w[ci,co,k1..k4]

#define XCISTRIDE 20736   // 12^4
#define OCOSTRIDE 390625  // 25^4

// w[ci][co][kk (81)] -> wt[kk][ci][co]
__global__ __launch_bounds__(256) void wtrans_kernel(const float* __restrict__ w,
                                                     float* __restrict__ wt) {
    int tid = blockIdx.x * 256 + threadIdx.x;
    if (tid >= 81 * 64 * 64) return;
    int co = tid & 63;
    int ci = (tid >> 6) & 63;
    int kk = tid >> 12;
    wt[tid] = w[(ci * 64 + co) * 81 + kk];
}

__global__ __launch_bounds__(256) void convt_kernel(const float* __restrict__ x,
                                                    const float* __restrict__ wt,
                                                    const float* __restrict__ bias,
                                                    float* __restrict__ out) {
    __shared__ float xs[8][64][14];   // [combo][ci][1+12+1 zero-padded]
    __shared__ float ot[64][26];      // [co][p4] staging for coalesced stores

    int bid = blockIdx.x;
    int p3 = bid % 25; int tq = bid / 25;
    int p2 = tq % 25; tq /= 25;
    int p1 = tq % 25; int bt = tq / 25;

    // valid taps per spatial dim 1..3: k == p (mod 2), i=(p-k)/2 in [0,12)
    int iv[3][2], kv[3][2], nt[3];
    int pp[3] = {p1, p2, p3};
    for (int d = 0; d < 3; ++d) {
        int n = 0;
        for (int k = (pp[d] & 1); k < 3; k += 2) {
            int i = (pp[d] - k) >> 1;
            if (i >= 0 && i < 12) { iv[d][n] = i; kv[d][n] = k; ++n; }
        }
        nt[d] = n;
    }
    int nc = nt[0] * nt[1] * nt[2];   // 1..8 combos
    int xb[8], wb[8];
    {
        int c = 0;
        for (int a = 0; a < nt[0]; ++a)
            for (int e = 0; e < nt[1]; ++e)
                for (int f = 0; f < nt[2]; ++f) {
                    xb[c] = ((((bt * 64) * 12 + iv[0][a]) * 12 + iv[1][e]) * 12 + iv[2][f]) * 12;
                    wb[c] = ((kv[0][a] * 3 + kv[1][e]) * 3 + kv[2][f]) * 3 * 4096;
                    ++c;
                }
    }

    int tid = threadIdx.x;
    // zero the pad columns (cols 0 and 13) for all 8 combo slots
    for (int f = tid; f < 8 * 64; f += 256) {
        xs[f >> 6][f & 63][0] = 0.0f;
        xs[f >> 6][f & 63][13] = 0.0f;
    }
    // stage x slices: xs[c][ci][1+i4] = x[b, ci, i1,i2,i3, i4]
    for (int c = 0; c < nc; ++c) {
        for (int f = tid; f < 768; f += 256) {
            int ci = f / 12;
            int i4 = f - ci * 12;
            xs[c][ci][1 + i4] = x[xb[c] + ci * XCISTRIDE + i4];
        }
    }
    __syncthreads();

    int co = tid & 63;     // lane id -> co (coalesced weight reads)
    int pg = tid >> 6;     // wave id -> p4 phase (wave-uniform -> LDS broadcasts)

    float bv = bias[co];
    float acc[7];
    #pragma unroll
    for (int j = 0; j < 7; ++j) acc[j] = bv;

    // p4 = pg + 4*j ; valid k4 share parity with pg.
    for (int c = 0; c < nc; ++c) {
        const float* wB = wt + wb[c] + co;
        const float* xC = &xs[c][0][0];
        if (pg & 1) {
            // k4 = 1
            int xoff = 1 + ((pg - 1) >> 1);
            const float* wp = wB + 4096;
            for (int ci = 0; ci < 64; ++ci) {
                float wv = wp[ci * 64];
                const float* xr = xC + ci * 14 + xoff;
                #pragma unroll
                for (int j = 0; j < 6; ++j) acc[j] = fmaf(xr[2 * j], wv, acc[j]);
            }
        } else {
            // k4 = 0 and k4 = 2
            int xoff0 = 1 + (pg >> 1);
            int xoff2 = 1 + ((pg - 2) >> 1);
            const float* wp0 = wB;
            const float* wp2 = wB + 2 * 4096;
            for (int ci = 0; ci < 64; ++ci) {
                float w0 = wp0[ci * 64];
                float w2 = wp2[ci * 64];
                const float* xr0 = xC + ci * 14 + xoff0;
                const float* xr2 = xC + ci * 14 + xoff2;
                #pragma unroll
                for (int j = 0; j < 6; ++j) {
                    acc[j] = fmaf(xr0[2 * j], w0, acc[j]);
                    acc[j] = fmaf(xr2[2 * j], w2, acc[j]);
                }
                if (pg == 0) {   // wave-uniform branch: j=6 only exists for pg==0
                    acc[6] = fmaf(xr0[12], w0, acc[6]);
                    acc[6] = fmaf(xr2[12], w2, acc[6]);
                }
            }
        }
    }

    int nj = (pg == 0) ? 7 : 6;
    for (int j = 0; j < nj; ++j) ot[co][pg + 4 * j] = acc[j];
    __syncthreads();

    // coalesced-ish store: 25-float runs per co
    int obase = (bt * 64) * OCOSTRIDE + ((p1 * 25 + p2) * 25 + p3) * 25;
    for (int f = tid; f < 1600; f += 256) {
        int c2 = f / 25;
        int p4 = f - c2 * 25;
        out[obase + c2 * OCOSTRIDE + p4] = ot[c2][p4];
    }
}

extern "C" void kernel_launch(void* const* d_in, const int* in_sizes, int n_in,
                              void* d_out, int out_size, void* d_ws, size_t ws_size,
                              hipStream_t stream) {
    const float* x    = (const float*)d_in[0];
    const float* w    = (const float*)d_in[1];
    const float* bias = (const float*)d_in[2];
    float* out = (float*)d_out;
    float* wt  = (float*)d_ws;   // 81*64*64*4 = 1.33 MB scratch

    wtrans_kernel<<<(81 * 64 * 64 + 255) / 256, 256, 0, stream>>>(w, wt);
    convt_kernel<<<4 * 25 * 25 * 25, 256, 0, stream>>>(x, wt, bias, out);
}

// Round 2
// 975.949 us; speedup vs baseline: 2.9823x; 2.9823x over previous
//
#include <hip/hip_runtime.h>

// ConvTranspose4d, stride 2: x[4,64,12^4] (*) w[64,64,3^4] -> out[4,64,25^4]
// Parity decomposition: p_d = 2*pe_d + r_d. For each parity class the valid taps are
// fixed -> dense implicit GEMM per class: out[co,pos] = sum_{ci,taps} w'[ci,co,k] * x[ci,pos-shift]
// Block = (b, p1, p2, class(r3,r4)); M=64 co, N=n3*n4 (<=169), K=64ci * taps, MFMA 16x16x32 bf16.

typedef short bf16x8 __attribute__((ext_vector_type(8)));
typedef float f32x4 __attribute__((ext_vector_type(4)));

__device__ __forceinline__ unsigned short f2bf(float f) {
    unsigned int u = __float_as_uint(f);
    u = (u + 0x7FFFu + ((u >> 16) & 1u)) >> 16;
    return (unsigned short)u;
}

// w[ci][co][kk(81)] fp32 -> wt[kk][co][ci] bf16
__global__ __launch_bounds__(256) void wtrans_kernel(const float* __restrict__ w,
                                                     unsigned short* __restrict__ wt) {
    int tid = blockIdx.x * 256 + threadIdx.x;
    if (tid >= 81 * 64 * 64) return;
    int ci = tid & 63;
    int co = (tid >> 6) & 63;
    int kk = tid >> 12;
    wt[tid] = f2bf(w[(ci * 64 + co) * 81 + kk]);
}

__global__ __launch_bounds__(256, 2) void convt_mfma_kernel(
        const float* __restrict__ x,
        const unsigned short* __restrict__ wt,
        const float* __restrict__ bias,
        float* __restrict__ out) {

    // xs: [ (i3+1)*14 + (i4+1) ][ ci ] bf16, zero halo at i+1 in {0,13}; 72-pad rows (bank spread)
    __shared__ unsigned short xs[196][72];   // 28224 B
    __shared__ unsigned short ws[4][64][72]; // 36864 B  (A-layout: [tap][co][ci])

    int bid = blockIdx.x;
    int cls = bid & 3;
    int tq = bid >> 2;
    int p2 = tq % 25; tq /= 25;
    int p1 = tq % 25; int b = tq / 25;
    int r3 = cls >> 1, r4 = cls & 1;
    int n3 = 13 - r3, n4 = 13 - r4;
    int N = n3 * n4;
    int nt3 = 2 - r3, nt4 = 2 - r4;
    int ntt = nt3 * nt4;

    int s3a[4], s4a[4];
    for (int tt = 0; tt < ntt; ++tt) { s3a[tt] = tt / nt4; s4a[tt] = tt - (tt / nt4) * nt4; }

    // valid (k,i) taps for dims 1,2 given p1,p2
    int i1v[2], k1v[2], n1 = 0;
    { int h = p1 >> 1, q = p1 & 1;
      for (int s = 0; s < 2 - q; ++s) { int i = h - s; if (0 <= i && i < 12) { i1v[n1] = i; k1v[n1] = 2 * s + q; ++n1; } } }
    int i2v[2], k2v[2], n2 = 0;
    { int h = p2 >> 1, q = p2 & 1;
      for (int s = 0; s < 2 - q; ++s) { int i = h - s; if (0 <= i && i < 12) { i2v[n2] = i; k2v[n2] = 2 * s + q; ++n2; } } }
    int ncomb = n1 * n2;

    int tid = threadIdx.x;
    int lane = tid & 63, wave = tid >> 6;
    int n_lo = lane & 15, quad = lane >> 4;

    // zero xs (halo stays zero; interior rewritten per combo)
    for (int f = tid; f < 196 * 72 / 2; f += 256) ((int*)xs)[f] = 0;

    // per-wave N-tiles: tiles wave, wave+4, wave+8
    int ntiles = (N + 15) >> 4;
    int nmyt = 0; int pe3a[3], pe4a[3], posa[3];
    for (int i = 0; i < 3; ++i) {
        int ti = wave + 4 * i;
        if (ti < ntiles) {
            int pos = ti * 16 + n_lo;
            int cp = pos < N ? pos : N - 1;
            pe3a[i] = cp / n4; pe4a[i] = cp - pe3a[i] * n4; posa[i] = pos;
            nmyt = i + 1;
        }
    }

    // seed accumulators with bias (each acc element is exactly one output element)
    float bvs[4][4];
    #pragma unroll
    for (int mt = 0; mt < 4; ++mt)
        #pragma unroll
        for (int rg = 0; rg < 4; ++rg)
            bvs[mt][rg] = bias[mt * 16 + quad * 4 + rg];
    f32x4 acc[3][4];
    #pragma unroll
    for (int i = 0; i < 3; ++i)
        #pragma unroll
        for (int mt = 0; mt < 4; ++mt)
            #pragma unroll
            for (int rg = 0; rg < 4; ++rg)
                acc[i][mt][rg] = bvs[mt][rg];

    int ci_s = tid >> 2, sub = tid & 3;
    __syncthreads();

    for (int c = 0; c < ncomb; ++c) {
        if (c) __syncthreads();
        int c1 = c / n2, c2 = c - (c / n2) * n2;
        int i1 = i1v[c1], k1 = k1v[c1];
        int i2 = i2v[c2], k2 = k2v[c2];

        // stage x slab: x[b, ci, i1, i2, :, :] -> xs[(i3+1)*14+(i4+1)][ci] bf16
        const float* xci = x + (size_t)b * 64 * 20736 + (size_t)ci_s * 20736
                             + i1 * 1728 + i2 * 144 + sub * 36;
        #pragma unroll
        for (int q = 0; q < 9; ++q) {
            float4 v = *(const float4*)(xci + q * 4);
            int e = sub * 36 + q * 4;
            #pragma unroll
            for (int u = 0; u < 4; ++u) {
                int ee = e + u;
                int a3 = ee / 12, a4 = ee - a3 * 12;
                xs[(a3 + 1) * 14 + (a4 + 1)][ci_s] = f2bf(((const float*)&v)[u]);
            }
        }
        // stage weight slices for this (k1,k2) and class taps: wt[kk][co][ci] -> ws[tt][co][ci]
        int kb = (k1 * 3 + k2) * 9;
        for (int tt = 0; tt < ntt; ++tt) {
            int kk = kb + (2 * s3a[tt] + r3) * 3 + (2 * s4a[tt] + r4);
            const bf16x8* src = (const bf16x8*)(wt + (size_t)kk * 4096);
            for (int rch = tid; rch < 512; rch += 256) {
                int co = rch >> 3, ce = (rch & 7) << 3;
                *(bf16x8*)&ws[tt][co][ce] = src[rch];
            }
        }
        __syncthreads();

        for (int tt = 0; tt < ntt; ++tt) {
            int s3 = s3a[tt], s4 = s4a[tt];
            #pragma unroll
            for (int kc = 0; kc < 2; ++kc) {
                int kof = kc * 32 + quad * 8;
                bf16x8 a0 = *(const bf16x8*)&ws[tt][n_lo     ][kof];
                bf16x8 a1 = *(const bf16x8*)&ws[tt][n_lo + 16][kof];
                bf16x8 a2 = *(const bf16x8*)&ws[tt][n_lo + 32][kof];
                bf16x8 a3 = *(const bf16x8*)&ws[tt][n_lo + 48][kof];
                #pragma unroll
                for (int i = 0; i < 3; ++i) {
                    if (i < nmyt) {
                        int row = (pe3a[i] - s3 + 1) * 14 + (pe4a[i] - s4 + 1);
                        bf16x8 bb = *(const bf16x8*)&xs[row][kof];
                        acc[i][0] = __builtin_amdgcn_mfma_f32_16x16x32_bf16(a0, bb, acc[i][0], 0, 0, 0);
                        acc[i][1] = __builtin_amdgcn_mfma_f32_16x16x32_bf16(a1, bb, acc[i][1], 0, 0, 0);
                        acc[i][2] = __builtin_amdgcn_mfma_f32_16x16x32_bf16(a2, bb, acc[i][2], 0, 0, 0);
                        acc[i][3] = __builtin_amdgcn_mfma_f32_16x16x32_bf16(a3, bb, acc[i][3], 0, 0, 0);
                    }
                }
            }
        }
    }

    // epilogue: D frag mapping col=lane&15 (pos), row=quad*4+reg (co within 16-chunk)
    size_t obase0 = (size_t)b * 64 * 390625 + (size_t)(p1 * 25 + p2) * 625;
    for (int i = 0; i < nmyt; ++i) {
        if (posa[i] < N) {
            int p3 = 2 * pe3a[i] + r3, p4 = 2 * pe4a[i] + r4;
            float* op = out + obase0 + p3 * 25 + p4;
            #pragma unroll
            for (int mt = 0; mt < 4; ++mt)
                #pragma unroll
                for (int rg = 0; rg < 4; ++rg)
                    op[(size_t)(mt * 16 + quad * 4 + rg) * 390625] = acc[i][mt][rg];
        }
    }
}

extern "C" void kernel_launch(void* const* d_in, const int* in_sizes, int n_in,
                              void* d_out, int out_size, void* d_ws, size_t ws_size,
                              hipStream_t stream) {
    const float* x    = (const float*)d_in[0];
    const float* w    = (const float*)d_in[1];
    const float* bias = (const float*)d_in[2];
    float* out = (float*)d_out;
    unsigned short* wt = (unsigned short*)d_ws;   // 81*64*64*2 = 663 KB scratch

    wtrans_kernel<<<(81 * 64 * 64 + 255) / 256, 256, 0, stream>>>(w, wt);
    convt_mfma_kernel<<<4 * 25 * 25 * 4, 256, 0, stream>>>(x, wt, bias, out);
}